// Round 4
// baseline (274.736 us; speedup 1.0000x reference)
//
#include <hip/hip_runtime.h>

typedef __attribute__((ext_vector_type(8))) short short8;
typedef __attribute__((ext_vector_type(4))) float floatx4;

#define MFMA __builtin_amdgcn_mfma_f32_16x16x32_bf16

// fp32 -> bf16 bits, round-to-nearest-even (finite inputs only)
__device__ inline short to_bf16s(float f) {
    unsigned u = __builtin_bit_cast(unsigned, f);
    unsigned r = u + 0x7FFFu + ((u >> 16) & 1u);
    return (short)(r >> 16);
}

// 8 consecutive floats -> bf16x8
__device__ inline short8 ld8f(const float* p) {
    float4 f0 = *(const float4*)p, f1 = *(const float4*)(p + 4);
    short8 r;
    r[0] = to_bf16s(f0.x); r[1] = to_bf16s(f0.y);
    r[2] = to_bf16s(f0.z); r[3] = to_bf16s(f0.w);
    r[4] = to_bf16s(f1.x); r[5] = to_bf16s(f1.y);
    r[6] = to_bf16s(f1.z); r[7] = to_bf16s(f1.w);
    return r;
}

// async 16B global -> LDS DMA (wave-uniform base + lane*16)
__device__ inline void dma16(const short* g, short* l) {
    __builtin_amdgcn_global_load_lds(
        (const __attribute__((address_space(1))) unsigned int*)(const void*)g,
        (__attribute__((address_space(3))) unsigned int*)(void*)l, 16, 0, 0);
}

// ===========================================================================
// MEGA: blocks [0,256)   : mlp2 GEMM 64x64 tiles (M=8192=b*2048+n, N=128=d),
//                          K=1536, in-kernel W2 transpose staging;
//                          epilogue writes HP0 [(n*4+b)][128] and HT0 [(b,d)][n].
//       blocks [256,512) : adjS rows = adj * (1/max(rowsum,1)), fp32->bf16.
//       blocks [512,608) : BigB_l [128 j'][256 k] = {Wr_l[k][j'] | Wo_l[k-128][j']}.
// ===========================================================================
struct MegaArgs {
    const float *x, *adj, *W2, *b2;
    const float *Wr0, *Wo0, *Wr1, *Wo1, *Wr2, *Wo2;
    short *adjS, *BB0, *BB1, *BB2, *HP0, *HT0;
};

__global__ __launch_bounds__(256) void mega(MegaArgs a) {
    __shared__ __align__(16) short lds[18432];  // 36 KB: dbuf 2 x (A 4608 + B 4608)
    int tid = threadIdx.x;
    int bid = blockIdx.x;

    if (bid < 256) {
        // ---------------- mlp2 ----------------
        int mt = bid >> 1, dt = bid & 1;
        int b = mt >> 5;             // 2048 rows per batch = 32 tiles of 64
        int n0 = (mt & 31) * 64;
        int srow = tid >> 3, scol = (tid & 7) * 8;
        const float* Abase = a.x + (size_t)(mt * 64) * 1536;
        int kk = tid >> 2, j0 = (tid & 3) * 16;  // B loader: thread covers (k=kk, d=j0..j0+16)
        const float* Bbase = a.W2 + (size_t)kk * 128 + dt * 64 + j0;

        short8 ra0 = ld8f(Abase + (size_t)srow * 1536 + scol);
        short8 ra1 = ld8f(Abase + (size_t)(srow + 32) * 1536 + scol);
        float4 bw0 = *(const float4*)(Bbase);
        float4 bw1 = *(const float4*)(Bbase + 4);
        float4 bw2 = *(const float4*)(Bbase + 8);
        float4 bw3 = *(const float4*)(Bbase + 12);

        floatx4 acc[2][2];
        #pragma unroll
        for (int i = 0; i < 2; ++i)
            #pragma unroll
            for (int j = 0; j < 2; ++j)
                #pragma unroll
                for (int r = 0; r < 4; ++r) acc[i][j][r] = 0.f;

        int lane = tid & 63, w = tid >> 6, wr = w >> 1, wc = w & 1;
        int quad = lane >> 4, l15 = lane & 15;

        for (int it = 0; it < 24; ++it) {
            short* As = lds + (it & 1) * 9216;
            short* Bs = As + 4608;
            *(short8*)(As + srow * 72 + scol) = ra0;
            *(short8*)(As + (srow + 32) * 72 + scol) = ra1;
            {
                const float* fw = (const float*)&bw0;
                #pragma unroll
                for (int e = 0; e < 4; ++e) Bs[(j0 + e) * 72 + kk] = to_bf16s(fw[e]);
                fw = (const float*)&bw1;
                #pragma unroll
                for (int e = 0; e < 4; ++e) Bs[(j0 + 4 + e) * 72 + kk] = to_bf16s(fw[e]);
                fw = (const float*)&bw2;
                #pragma unroll
                for (int e = 0; e < 4; ++e) Bs[(j0 + 8 + e) * 72 + kk] = to_bf16s(fw[e]);
                fw = (const float*)&bw3;
                #pragma unroll
                for (int e = 0; e < 4; ++e) Bs[(j0 + 12 + e) * 72 + kk] = to_bf16s(fw[e]);
            }
            __syncthreads();
            if (it + 1 < 24) {
                int ko = (it + 1) * 64;
                ra0 = ld8f(Abase + (size_t)srow * 1536 + ko + scol);
                ra1 = ld8f(Abase + (size_t)(srow + 32) * 1536 + ko + scol);
                const float* Bp = Bbase + (size_t)ko * 128;
                bw0 = *(const float4*)(Bp);
                bw1 = *(const float4*)(Bp + 4);
                bw2 = *(const float4*)(Bp + 8);
                bw3 = *(const float4*)(Bp + 12);
            }
            const short* Arow = As + (wr * 32 + l15) * 72;
            const short* Brow = Bs + (wc * 32 + l15) * 72;
            #pragma unroll
            for (int ks = 0; ks < 2; ++ks) {
                int kof = ks * 32 + quad * 8;
                short8 a0 = *(const short8*)(Arow + kof);
                short8 a1 = *(const short8*)(Arow + 16 * 72 + kof);
                short8 b0 = *(const short8*)(Brow + kof);
                short8 b1 = *(const short8*)(Brow + 16 * 72 + kof);
                acc[0][0] = MFMA(a0, b0, acc[0][0], 0, 0, 0);
                acc[0][1] = MFMA(a0, b1, acc[0][1], 0, 0, 0);
                acc[1][0] = MFMA(a1, b0, acc[1][0], 0, 0, 0);
                acc[1][1] = MFMA(a1, b1, acc[1][1], 0, 0, 0);
            }
            __syncthreads();
        }
        // OUT bounce (stride 72) then coalesced HP0 / HT0 writes
        #pragma unroll
        for (int ti = 0; ti < 2; ++ti)
            #pragma unroll
            for (int tj = 0; tj < 2; ++tj) {
                int col = wc * 32 + tj * 16 + l15;
                float bv = a.b2[dt * 64 + col];
                int row0 = wr * 32 + ti * 16 + quad * 4;
                #pragma unroll
                for (int r = 0; r < 4; ++r)
                    lds[(row0 + r) * 72 + col] = to_bf16s(acc[ti][tj][r] + bv);
            }
        __syncthreads();
        {   // HP0: rows (node*4+b), 128 cols; this block covers cols dt*64..+64
            int nl = tid >> 2, c0 = (tid & 3) * 16;
            short8 v0 = *(const short8*)(lds + nl * 72 + c0);
            short8 v1 = *(const short8*)(lds + nl * 72 + c0 + 8);
            short* dst = a.HP0 + (size_t)((n0 + nl) * 4 + b) * 128 + dt * 64 + c0;
            *(short8*)(dst) = v0;
            *(short8*)(dst + 8) = v1;
        }
        {   // HT0: rows (b*128 + d), 2048 cols = n
            int d = tid >> 2, nh = (tid & 3) * 16;
            short tmp[16];
            #pragma unroll
            for (int i = 0; i < 16; ++i) tmp[i] = lds[(nh + i) * 72 + d];
            short* dst = a.HT0 + (size_t)(b * 128 + dt * 64 + d) * 2048 + n0 + nh;
            *(short8*)(dst) = *(const short8*)(tmp);
            *(short8*)(dst + 8) = *(const short8*)(tmp + 8);
        }
    } else if (bid < 512) {
        // ---------------- adjS ----------------
        float* red = (float*)lds;
        int base = (bid - 256) * 8;
        for (int r = 0; r < 8; ++r) {
            int row = base + r;
            const float* src = a.adj + (size_t)row * 2048 + tid * 8;
            float4 f0 = *(const float4*)src;
            float4 f1 = *(const float4*)(src + 4);
            float s = f0.x + f0.y + f0.z + f0.w + f1.x + f1.y + f1.z + f1.w;
            red[tid] = s;
            __syncthreads();
            for (int st = 128; st > 0; st >>= 1) {
                if (tid < st) red[tid] += red[tid + st];
                __syncthreads();
            }
            float dsum = red[0];
            __syncthreads();
            dsum = dsum < 1.f ? 1.f : dsum;
            float inv = 1.f / dsum;
            short8 o;
            o[0] = to_bf16s(f0.x * inv); o[1] = to_bf16s(f0.y * inv);
            o[2] = to_bf16s(f0.z * inv); o[3] = to_bf16s(f0.w * inv);
            o[4] = to_bf16s(f1.x * inv); o[5] = to_bf16s(f1.y * inv);
            o[6] = to_bf16s(f1.z * inv); o[7] = to_bf16s(f1.w * inv);
            *(short8*)(a.adjS + (size_t)row * 2048 + tid * 8) = o;
        }
    } else {
        // ---------------- BigB ----------------
        int u = bid - 512;
        int l = u >> 5, v = u & 31;
        int j0 = (v & 3) * 32, k0 = (v >> 2) * 32;
        const float* Wr = l == 0 ? a.Wr0 : l == 1 ? a.Wr1 : a.Wr2;
        const float* Wo = l == 0 ? a.Wo0 : l == 1 ? a.Wo1 : a.Wo2;
        short* BB = l == 0 ? a.BB0 : l == 1 ? a.BB1 : a.BB2;
        short(*tile)[33] = (short(*)[33])lds;
        int tx = tid & 31, ty = tid >> 5;
        for (int i = ty; i < 32; i += 8) {
            int k = k0 + i;
            const float* srow = (k < 128) ? (Wr + (size_t)k * 128)
                                          : (Wo + (size_t)(k - 128) * 128);
            tile[i][tx] = to_bf16s(srow[j0 + tx]);
        }
        __syncthreads();
        for (int i = ty; i < 32; i += 8)
            BB[(size_t)(j0 + i) * 256 + k0 + tx] = tile[tx][i];
    }
}

// ===========================================================================
// layer: fused SAGE layer. grid (32, 4): blockIdx.x = 64-node tile, .y = batch.
// Stage 1: AGG[64 nodes][128 d] = adjS[nodes][k] @ HTin[(b,d)][k]^T, K=2048.
// Stage 2: OUT[64][128] = [AGG | Hp] @ BB^T + bias (+relu), K=256.
// Writes HPout [(n*4+b)][128] and (optional) HTout [(b,d)][n].
// ===========================================================================
__global__ __launch_bounds__(256) void layer(
    const short* __restrict__ adjS, const short* __restrict__ HTin,
    const short* __restrict__ HPin, const short* __restrict__ BB,
    const float* __restrict__ bias, short* __restrict__ HPout,
    short* __restrict__ HTout, int relu) {
    __shared__ __align__(16) short As[64 * 64];    // 8 KB
    __shared__ __align__(16) short Bs[128 * 64];   // 16 KB
    __shared__ __align__(16) short A2[64 * 264];   // 33.8 KB: [AGG k0:128 | Hp k128:256] pad 8
    int tid = threadIdx.x;
    int mt = blockIdx.x, b = blockIdx.y;
    int lane = tid & 63, w = tid >> 6, wr = w >> 1, wc = w & 1;
    int quad = lane >> 4, l15 = lane & 15;

    const short* Ab = adjS + (size_t)(mt * 64 + (tid >> 3)) * 2048 + (tid & 7) * 8;
    const short* Bb = HTin + (size_t)(b * 128 + (tid >> 3)) * 2048 + (tid & 7) * 8;
    short* Al = As + tid * 8;
    short* Bl = Bs + tid * 8;

    floatx4 acc[2][4];
    #pragma unroll
    for (int i = 0; i < 2; ++i)
        #pragma unroll
        for (int j = 0; j < 4; ++j)
            #pragma unroll
            for (int r = 0; r < 4; ++r) acc[i][j][r] = 0.f;

    // ---- stage 1: K = 2048, 32 iters ----
    for (int it = 0; it < 32; ++it) {
        dma16(Ab + it * 64, Al);
        dma16(Ab + it * 64 + (size_t)32 * 2048, Al + 2048);
        #pragma unroll
        for (int r = 0; r < 4; ++r)
            dma16(Bb + it * 64 + (size_t)(r * 32) * 2048, Bl + r * 2048);
        __syncthreads();
        const short* Ar = As + (wr * 32 + l15) * 64;
        const short* Br = Bs + (wc * 64 + l15) * 64;
        #pragma unroll
        for (int ks = 0; ks < 2; ++ks) {
            int kof = ks * 32 + quad * 8;
            short8 af[2], bf[4];
            #pragma unroll
            for (int i = 0; i < 2; ++i) af[i] = *(const short8*)(Ar + i * 16 * 64 + kof);
            #pragma unroll
            for (int j = 0; j < 4; ++j) bf[j] = *(const short8*)(Br + j * 16 * 64 + kof);
            #pragma unroll
            for (int i = 0; i < 2; ++i)
                #pragma unroll
                for (int j = 0; j < 4; ++j)
                    acc[i][j] = MFMA(af[i], bf[j], acc[i][j], 0, 0, 0);
        }
        __syncthreads();
    }

    // AGG -> A2[:, 0:128] (bf16), C/D layout col=lane&15 row=quad*4+reg
    #pragma unroll
    for (int ti = 0; ti < 2; ++ti)
        #pragma unroll
        for (int tj = 0; tj < 4; ++tj) {
            int jc = wc * 64 + tj * 16 + l15;
            int row0 = wr * 32 + ti * 16 + quad * 4;
            #pragma unroll
            for (int r = 0; r < 4; ++r)
                A2[(row0 + r) * 264 + jc] = to_bf16s(acc[ti][tj][r]);
        }
    // Hp tile -> A2[:, 128:256]
    {
        int m = tid >> 2, c0 = (tid & 3) * 32;
        const short* src = HPin + (size_t)((mt * 64 + m) * 4 + b) * 128 + c0;
        short* dst = A2 + m * 264 + 128 + c0;
        #pragma unroll
        for (int q = 0; q < 4; ++q)
            *(short8*)(dst + q * 8) = *(const short8*)(src + q * 8);
    }
    __syncthreads();

    // ---- stage 2: K = 256, 4 iters ----
    floatx4 acc2[2][4];
    #pragma unroll
    for (int i = 0; i < 2; ++i)
        #pragma unroll
        for (int j = 0; j < 4; ++j)
            #pragma unroll
            for (int r = 0; r < 4; ++r) acc2[i][j][r] = 0.f;

    for (int kc = 0; kc < 4; ++kc) {
        #pragma unroll
        for (int r = 0; r < 4; ++r)
            dma16(BB + (size_t)((tid >> 3) + r * 32) * 256 + kc * 64 + (tid & 7) * 8,
                  Bl + r * 2048);
        __syncthreads();
        const short* A2r = A2 + (wr * 32 + l15) * 264 + kc * 64;
        const short* Br = Bs + (wc * 64 + l15) * 64;
        #pragma unroll
        for (int ks = 0; ks < 2; ++ks) {
            int kof = ks * 32 + quad * 8;
            short8 af[2], bf[4];
            #pragma unroll
            for (int i = 0; i < 2; ++i) af[i] = *(const short8*)(A2r + i * 16 * 264 + kof);
            #pragma unroll
            for (int j = 0; j < 4; ++j) bf[j] = *(const short8*)(Br + j * 16 * 64 + kof);
            #pragma unroll
            for (int i = 0; i < 2; ++i)
                #pragma unroll
                for (int j = 0; j < 4; ++j)
                    acc2[i][j] = MFMA(af[i], bf[j], acc2[i][j], 0, 0, 0);
        }
        __syncthreads();
    }

    // epilogue: OUT (stride 136) into A2 region, then coalesced global writes
    #pragma unroll
    for (int ti = 0; ti < 2; ++ti)
        #pragma unroll
        for (int tj = 0; tj < 4; ++tj) {
            int jc = wc * 64 + tj * 16 + l15;
            float bv = bias[jc];
            int row0 = wr * 32 + ti * 16 + quad * 4;
            #pragma unroll
            for (int r = 0; r < 4; ++r) {
                float xv = acc2[ti][tj][r] + bv;
                if (relu) xv = xv > 0.f ? xv : 0.f;
                A2[(row0 + r) * 136 + jc] = to_bf16s(xv);
            }
        }
    __syncthreads();
    {
        int m = tid >> 2, c0 = (tid & 3) * 32;
        const short* src = A2 + m * 136 + c0;
        short* dst = HPout + (size_t)((mt * 64 + m) * 4 + b) * 128 + c0;
        #pragma unroll
        for (int q = 0; q < 4; ++q)
            *(short8*)(dst + q * 8) = *(const short8*)(src + q * 8);
    }
    if (HTout) {
        int d = tid >> 1, nh = (tid & 1) * 32;
        short tmp[32];
        #pragma unroll
        for (int i = 0; i < 32; ++i) tmp[i] = A2[(nh + i) * 136 + d];
        short* dst = HTout + (size_t)(b * 128 + d) * 2048 + mt * 64 + nh;
        #pragma unroll
        for (int q = 0; q < 4; ++q)
            *(short8*)(dst + q * 8) = *(const short8*)(tmp + q * 8);
    }
}

// ===========================================================================
// mlp1: out[b*2048+n][c] = HP3[(n*4+b)][k] @ W1[k][c] + b[c].  128x128 tiles,
// K=128 (2 iters), A via dma16, B via in-kernel W1 transpose staging. fp32 out.
// ===========================================================================
__global__ __launch_bounds__(256) void mlp1k(
    const short* __restrict__ HP3, const float* __restrict__ W1,
    const float* __restrict__ bias, float* __restrict__ out) {
    __shared__ __align__(16) short As[128 * 64];
    __shared__ __align__(16) short Bs[128 * 64];
    int tid = threadIdx.x;
    int blockM = blockIdx.x * 128;
    int blockN = blockIdx.y * 128;
    const short* Ab = HP3 + (size_t)(blockM + (tid >> 3)) * 128 + (tid & 7) * 8;
    short* Al = As + tid * 8;
    int kk = tid & 63, c0 = (tid >> 6) * 32;
    const float* Wb = W1 + (size_t)kk * 1536 + blockN + c0;

    floatx4 acc[4][4];
    #pragma unroll
    for (int i = 0; i < 4; ++i)
        #pragma unroll
        for (int j = 0; j < 4; ++j)
            #pragma unroll
            for (int r = 0; r < 4; ++r) acc[i][j][r] = 0.f;

    int lane = tid & 63, w = tid >> 6, wr = w >> 1, wc = w & 1;
    int quad = lane >> 4, l15 = lane & 15;

    for (int it = 0; it < 2; ++it) {
        #pragma unroll
        for (int r = 0; r < 4; ++r)
            dma16(Ab + it * 64 + (size_t)(r * 32) * 128, Al + r * 2048);
        const float* Wp = Wb + (size_t)it * 64 * 1536;
        float4 f[8];
        #pragma unroll
        for (int q = 0; q < 8; ++q) f[q] = *(const float4*)(Wp + q * 4);
        #pragma unroll
        for (int q = 0; q < 8; ++q) {
            const float* fe = (const float*)&f[q];
            #pragma unroll
            for (int e = 0; e < 4; ++e)
                Bs[(c0 + q * 4 + e) * 64 + kk] = to_bf16s(fe[e]);
        }
        __syncthreads();
        const short* Ar = As + (wr * 64 + l15) * 64;
        const short* Br = Bs + (wc * 64 + l15) * 64;
        #pragma unroll
        for (int ks = 0; ks < 2; ++ks) {
            int kof = ks * 32 + quad * 8;
            short8 af[4], bf[4];
            #pragma unroll
            for (int i = 0; i < 4; ++i) af[i] = *(const short8*)(Ar + i * 16 * 64 + kof);
            #pragma unroll
            for (int j = 0; j < 4; ++j) bf[j] = *(const short8*)(Br + j * 16 * 64 + kof);
            #pragma unroll
            for (int i = 0; i < 4; ++i)
                #pragma unroll
                for (int j = 0; j < 4; ++j)
                    acc[i][j] = MFMA(af[i], bf[j], acc[i][j], 0, 0, 0);
        }
        __syncthreads();
    }

    #pragma unroll
    for (int ti = 0; ti < 4; ++ti)
        #pragma unroll
        for (int tj = 0; tj < 4; ++tj) {
            int col = blockN + wc * 64 + tj * 16 + l15;
            float bv = bias[col];
            int row0 = blockM + wr * 64 + ti * 16 + quad * 4;
            #pragma unroll
            for (int r = 0; r < 4; ++r) {
                int mp = row0 + r;  // n*4+b
                int orow = ((mp & 3) << 11) | (mp >> 2);
                out[(size_t)orow * 1536 + col] = acc[ti][tj][r] + bv;
            }
        }
}

// ===========================================================================
// Launch: 5 dispatches total.
// ===========================================================================
extern "C" void kernel_launch(void* const* d_in, const int* in_sizes, int n_in,
                              void* d_out, int out_size, void* d_ws, size_t ws_size,
                              hipStream_t stream) {
    const float* x      = (const float*)d_in[0];
    const float* adj    = (const float*)d_in[1];
    const float* W_mlp2 = (const float*)d_in[2];
    const float* b_mlp2 = (const float*)d_in[3];
    const float* Wr1    = (const float*)d_in[4];
    const float* Wo1    = (const float*)d_in[5];
    const float* b1     = (const float*)d_in[6];
    const float* Wr2    = (const float*)d_in[7];
    const float* Wo2    = (const float*)d_in[8];
    const float* b2     = (const float*)d_in[9];
    const float* Wr3    = (const float*)d_in[10];
    const float* Wo3    = (const float*)d_in[11];
    const float* b3     = (const float*)d_in[12];
    const float* W_mlp1 = (const float*)d_in[13];
    const float* b_mlp1 = (const float*)d_in[14];
    float* out = (float*)d_out;

    char* ws = (char*)d_ws;
    size_t off = 0;
    auto alloc = [&](size_t bytes) -> char* {
        char* p = ws + off;
        off = (off + bytes + 255) & ~(size_t)255;
        return p;
    };
    short* adjS = (short*)alloc((size_t)2048 * 2048 * 2);  // 8 MB
    short* BB[3];
    for (int l = 0; l < 3; ++l) BB[l] = (short*)alloc(128 * 256 * 2);
    short* HPa = (short*)alloc((size_t)8192 * 128 * 2);    // 2 MB
    short* HPb = (short*)alloc((size_t)8192 * 128 * 2);
    short* HTa = (short*)alloc((size_t)512 * 2048 * 2);    // 2 MB
    short* HTb = (short*)alloc((size_t)512 * 2048 * 2);

    MegaArgs ma{x, adj, W_mlp2, b_mlp2, Wr1, Wo1, Wr2, Wo2, Wr3, Wo3,
                adjS, BB[0], BB[1], BB[2], HPa, HTa};
    mega<<<608, 256, 0, stream>>>(ma);
    layer<<<dim3(32, 4), 256, 0, stream>>>(adjS, HTa, HPa, BB[0], b1, HPb, HTb, 1);
    layer<<<dim3(32, 4), 256, 0, stream>>>(adjS, HTb, HPb, BB[1], b2, HPa, HTa, 1);
    layer<<<dim3(32, 4), 256, 0, stream>>>(adjS, HTa, HPa, BB[2], b3, HPb, nullptr, 0);
    mlp1k<<<dim3(64, 12), 256, 0, stream>>>(HPb, W_mlp1, b_mlp1, out);
}